// Round 15
// baseline (275.146 us; speedup 1.0000x reference)
//
#include <hip/hip_runtime.h>
#include <math.h>

// Problem constants (B,C,H,W fixed by the reference)
#define BB 4
#define CC 16
#define HH 256
#define WW 256
#define NN (HH*WW)        // 65536 pixels per batch
#define MM 256            // superpixels
#define CROW 20           // padded center row: c[0..17], [18]=||c||^2, [19]=pad
#define PROW 20           // pixel row: p[0..17], [18]=||p||^2, [19]=1.0
#define PIX 32            // pixels per sub-tile
#define TSUB 4            // sub-tiles per block (128 px/block)
#define PIXPERBLK (PIX*TSUB)
#define CHUNKS (NN/PIXPERBLK)   // 512 chunks per batch

typedef float f32x2 __attribute__((ext_vector_type(2)));
typedef float f32x4v __attribute__((ext_vector_type(4)));
typedef short bf16x8 __attribute__((ext_vector_type(8)));

__device__ __forceinline__ f32x2 mk2(float a, float b) { f32x2 r; r.x = a; r.y = b; return r; }
__device__ __forceinline__ f32x2 pk_fma(f32x2 a, f32x2 b, f32x2 c) {
    return __builtin_elementwise_fma(a, b, c);
}

// fp32 -> bf16 bits (RNE) and back, via bit ops (no API dependence)
__device__ __forceinline__ unsigned short f2bf(float f) {
    unsigned u = __builtin_bit_cast(unsigned, f);
    unsigned r = (u + 0x7FFFu + ((u >> 16) & 1u)) >> 16;
    return (unsigned short)r;
}
__device__ __forceinline__ float bf2f(unsigned short v) {
    unsigned u = ((unsigned)v) << 16;
    return __builtin_bit_cast(float, u);
}

// ---------------------------------------------------------------------------
// Initial centers: 16x16 block means of features + analytic xy means + ||c||^2
// ---------------------------------------------------------------------------
__global__ void init_centers(const float* __restrict__ feat, float* __restrict__ cbuf)
{
    const int b    = blockIdx.x >> 8;
    const int m    = blockIdx.x & 255;
    const int lane = threadIdx.x;          // 0..63
    const int sy = m >> 4, sx = m & 15;

    float cvals[16];
#pragma unroll
    for (int d = 0; d < 16; ++d) {
        float v = 0.f;
#pragma unroll
        for (int k = 0; k < 4; ++k) {
            int q  = lane + (k << 6);            // 0..255 within 16x16 block
            int py = q >> 4, px = q & 15;
            int n  = (sy*16 + py)*WW + sx*16 + px;
            v += feat[((b*CC + d) << 16) + n];
        }
#pragma unroll
        for (int off = 32; off; off >>= 1) v += __shfl_down(v, off);
        cvals[d] = v * (1.f/256.f);
    }
    if (lane == 0) {
        float* row = cbuf + (b*MM + m)*CROW;
        float cn2 = 0.f;
#pragma unroll
        for (int d = 0; d < 16; ++d) { row[d] = cvals[d]; cn2 = fmaf(cvals[d], cvals[d], cn2); }
        float cx = (sx*16 + 7.5f) * (1.f/256.f);
        float cy = (sy*16 + 7.5f) * (1.f/256.f);
        row[16] = cx; row[17] = cy;
        cn2 = fmaf(cx, cx, cn2);
        cn2 = fmaf(cy, cy, cn2);
        row[18] = cn2;
        row[19] = 0.f;
    }
}

// ---------------------------------------------------------------------------
// Pre-transpose: pixel rows {p[0..17], ||p||^2, 1.0} into contiguous
// ptbuf[b][n][20] in d_ws.
// ---------------------------------------------------------------------------
__global__ void build_pt(const float* __restrict__ feat, float* __restrict__ ptbuf)
{
    const int b = blockIdx.x >> 8;
    const int n = ((blockIdx.x & 255) << 8) | threadIdx.x;
    float v[16];
#pragma unroll
    for (int d = 0; d < 16; ++d) v[d] = feat[((b*CC + d) << 16) + n];
    float x = (float)(n & 255) * (1.f/256.f);
    float y = (float)(n >> 8) * (1.f/256.f);
    float pn2 = 0.f;
#pragma unroll
    for (int d = 0; d < 16; ++d) pn2 = fmaf(v[d], v[d], pn2);
    pn2 = fmaf(x, x, pn2);
    pn2 = fmaf(y, y, pn2);
    float4* row = reinterpret_cast<float4*>(ptbuf + (size_t)(b*NN + n)*PROW);
    row[0] = make_float4(v[0],  v[1],  v[2],  v[3]);
    row[1] = make_float4(v[4],  v[5],  v[6],  v[7]);
    row[2] = make_float4(v[8],  v[9],  v[10], v[11]);
    row[3] = make_float4(v[12], v[13], v[14], v[15]);
    row[4] = make_float4(x, y, pn2, 1.0f);
}

// ---------------------------------------------------------------------------
// Non-final iteration kernel: PROVEN round-9 KM=2 path (83 us/dispatch).
// ---------------------------------------------------------------------------
__global__ __launch_bounds__(256, 3)
void ssn_nf(const float* __restrict__ ptbuf, const float* __restrict__ cbuf,
            float* __restrict__ pp)
{
    __shared__ __align__(16) float pls[PIXPERBLK*PROW];   // 10240 B
    __shared__ float ssum_s[TSUB][4][16];                 //  1024 B
    __shared__ float w_s[TSUB][PIX];                      //   512 B
    __shared__ float xfer[128*41];                        // 20992 B

    const int tid    = threadIdx.x;
    const int b      = blockIdx.x >> 9;
    const int chunk  = blockIdx.x & (CHUNKS-1);
    const int n_base = chunk * PIXPERBLK;
    const int lane   = tid & 63;
    const int wv     = tid >> 6;
    const int mlo    = tid & 127;          // m0 = mlo, m1 = mlo + 128
    const int pxbase = (tid >> 7) << 4;    // 0 or 16

    {
        const float4* src = reinterpret_cast<const float4*>(
            ptbuf + (size_t)(b*NN + n_base)*PROW);
#pragma unroll
        for (int k = 0; k < 3; ++k) {
            int f = tid + (k << 8);
            if (f < PIXPERBLK*PROW/4)
                reinterpret_cast<float4*>(pls)[f] = src[f];
        }
    }

    f32x2 cp0[9], cp1[9]; float cn20, cn21;
    {
        const float4* cv = reinterpret_cast<const float4*>(cbuf + (b*MM + mlo)*CROW);
        float4 a0 = cv[0], a1 = cv[1], a2 = cv[2], a3 = cv[3], a4 = cv[4];
        cp0[0]=mk2(a0.x,a0.y); cp0[1]=mk2(a0.z,a0.w);
        cp0[2]=mk2(a1.x,a1.y); cp0[3]=mk2(a1.z,a1.w);
        cp0[4]=mk2(a2.x,a2.y); cp0[5]=mk2(a2.z,a2.w);
        cp0[6]=mk2(a3.x,a3.y); cp0[7]=mk2(a3.z,a3.w);
        cp0[8]=mk2(a4.x,a4.y); cn20=a4.z;
    }
    {
        const float4* cv = reinterpret_cast<const float4*>(cbuf + (b*MM + mlo + 128)*CROW);
        float4 a0 = cv[0], a1 = cv[1], a2 = cv[2], a3 = cv[3], a4 = cv[4];
        cp1[0]=mk2(a0.x,a0.y); cp1[1]=mk2(a0.z,a0.w);
        cp1[2]=mk2(a1.x,a1.y); cp1[3]=mk2(a1.z,a1.w);
        cp1[4]=mk2(a2.x,a2.y); cp1[5]=mk2(a2.z,a2.w);
        cp1[6]=mk2(a3.x,a3.y); cp1[7]=mk2(a3.z,a3.w);
        cp1[8]=mk2(a4.x,a4.y); cn21=a4.z;
    }

    f32x2 acc0[10], acc1[10];
#pragma unroll
    for (int k = 0; k < 10; ++k) { acc0[k] = mk2(0.f,0.f); acc1[k] = mk2(0.f,0.f); }

    const int pxo4 = ((lane&1)<<3) | ((lane&2)<<1) | ((lane&4)>>1) | ((lane&8)>>3);

    __syncthreads();   // pls ready

    for (int t = 0; t < TSUB; ++t) {
        float e0[16], e1[16];
#pragma unroll
        for (int k = 0; k < 16; ++k) {
            const float4* pv = reinterpret_cast<const float4*>(
                &pls[(t*PIX + pxbase + k)*PROW]);
            float4 q0 = pv[0], q1 = pv[1], q2 = pv[2], q3 = pv[3], q4 = pv[4];
            f32x2 u0=mk2(q0.x,q0.y), u1=mk2(q0.z,q0.w), u2=mk2(q1.x,q1.y),
                  u3=mk2(q1.z,q1.w), u4=mk2(q2.x,q2.y), u5=mk2(q2.z,q2.w),
                  u6=mk2(q3.x,q3.y), u7=mk2(q3.z,q3.w), u8=mk2(q4.x,q4.y);
            f32x2 d0 = mk2(0.f,0.f), d1 = mk2(0.f,0.f);
            d0 = pk_fma(u0, cp0[0], d0);  d1 = pk_fma(u0, cp1[0], d1);
            d0 = pk_fma(u1, cp0[1], d0);  d1 = pk_fma(u1, cp1[1], d1);
            d0 = pk_fma(u2, cp0[2], d0);  d1 = pk_fma(u2, cp1[2], d1);
            d0 = pk_fma(u3, cp0[3], d0);  d1 = pk_fma(u3, cp1[3], d1);
            d0 = pk_fma(u4, cp0[4], d0);  d1 = pk_fma(u4, cp1[4], d1);
            d0 = pk_fma(u5, cp0[5], d0);  d1 = pk_fma(u5, cp1[5], d1);
            d0 = pk_fma(u6, cp0[6], d0);  d1 = pk_fma(u6, cp1[6], d1);
            d0 = pk_fma(u7, cp0[7], d0);  d1 = pk_fma(u7, cp1[7], d1);
            d0 = pk_fma(u8, cp0[8], d0);  d1 = pk_fma(u8, cp1[8], d1);
            float d20 = fmaf(-2.f, d0.x + d0.y, q4.z + cn20);
            float d21 = fmaf(-2.f, d1.x + d1.y, q4.z + cn21);
            e0[k] = __expf(-__builtin_amdgcn_sqrtf(fmaxf(d20, 1e-12f)));
            e1[k] = __expf(-__builtin_amdgcn_sqrtf(fmaxf(d21, 1e-12f)));
        }

        float s[8];
        {
            const bool hi = (lane & 1);
#pragma unroll
            for (int k = 0; k < 8; ++k) {
                float a  = e0[k]   + e1[k];
                float bq = e0[k+8] + e1[k+8];
                float recv = __shfl_xor(hi ? a : bq, 1);
                s[k] = (hi ? bq : a) + recv;
            }
        }
#define RS_ROUND(MASK, H) { const bool hi = (lane & (MASK)); \
        _Pragma("unroll") \
        for (int k = 0; k < (H); ++k) { \
            float a = s[k], bq = s[k+(H)]; \
            float recv = __shfl_xor(hi ? a : bq, (MASK)); \
            s[k] = (hi ? bq : a) + recv; } }
        RS_ROUND(2, 4)
        RS_ROUND(4, 2)
        RS_ROUND(8, 1)
#undef RS_ROUND
        s[0] += __shfl_xor(s[0], 16);
        s[0] += __shfl_xor(s[0], 32);
        if (lane < 16) ssum_s[t][wv][pxo4] = s[0];
        __syncthreads();
        if (tid < 32) {
            int h = tid >> 4, p4 = tid & 15;
            w_s[t][tid] = 1.0f / (ssum_s[t][2*h][p4] + ssum_s[t][2*h+1][p4]);
        }
        __syncthreads();

#pragma unroll
        for (int k = 0; k < 16; ++k) {
            const float4* pv = reinterpret_cast<const float4*>(
                &pls[(t*PIX + pxbase + k)*PROW]);
            float4 q0 = pv[0], q1 = pv[1], q2 = pv[2], q3 = pv[3], q4 = pv[4];
            float w = w_s[t][pxbase + k];
            float w0 = e0[k]*w, w1 = e1[k]*w;
            f32x2 ew0 = mk2(w0, w0), ew1 = mk2(w1, w1);
            f32x2 u0=mk2(q0.x,q0.y), u1=mk2(q0.z,q0.w), u2=mk2(q1.x,q1.y),
                  u3=mk2(q1.z,q1.w), u4=mk2(q2.x,q2.y), u5=mk2(q2.z,q2.w),
                  u6=mk2(q3.x,q3.y), u7=mk2(q3.z,q3.w), u8=mk2(q4.x,q4.y),
                  u9=mk2(q4.z,q4.w);
            acc0[0] = pk_fma(ew0, u0, acc0[0]);  acc1[0] = pk_fma(ew1, u0, acc1[0]);
            acc0[1] = pk_fma(ew0, u1, acc0[1]);  acc1[1] = pk_fma(ew1, u1, acc1[1]);
            acc0[2] = pk_fma(ew0, u2, acc0[2]);  acc1[2] = pk_fma(ew1, u2, acc1[2]);
            acc0[3] = pk_fma(ew0, u3, acc0[3]);  acc1[3] = pk_fma(ew1, u3, acc1[3]);
            acc0[4] = pk_fma(ew0, u4, acc0[4]);  acc1[4] = pk_fma(ew1, u4, acc1[4]);
            acc0[5] = pk_fma(ew0, u5, acc0[5]);  acc1[5] = pk_fma(ew1, u5, acc1[5]);
            acc0[6] = pk_fma(ew0, u6, acc0[6]);  acc1[6] = pk_fma(ew1, u6, acc1[6]);
            acc0[7] = pk_fma(ew0, u7, acc0[7]);  acc1[7] = pk_fma(ew1, u7, acc1[7]);
            acc0[8] = pk_fma(ew0, u8, acc0[8]);  acc1[8] = pk_fma(ew1, u8, acc1[8]);
            acc0[9] = pk_fma(ew0, u9, acc0[9]);  acc1[9] = pk_fma(ew1, u9, acc1[9]);
        }
    }

    // combine px-half partials across partner threads (tid <-> tid^128)
    if (tid >= 128) {
        float* xb = &xfer[(tid - 128)*41];
#pragma unroll
        for (int j = 0; j < 10; ++j) { xb[2*j]    = acc0[j].x; xb[2*j+1]    = acc0[j].y; }
#pragma unroll
        for (int j = 0; j < 10; ++j) { xb[20+2*j] = acc1[j].x; xb[20+2*j+1] = acc1[j].y; }
    }
    __syncthreads();
    if (tid < 128) {
        const float* xb = &xfer[tid*41];
#pragma unroll
        for (int j = 0; j < 10; ++j) { acc0[j].x += xb[2*j];    acc0[j].y += xb[2*j+1]; }
#pragma unroll
        for (int j = 0; j < 10; ++j) { acc1[j].x += xb[20+2*j]; acc1[j].y += xb[20+2*j+1]; }

        float* dst0 = pp + ((size_t)(b*CHUNKS + chunk)*MM + mlo)*PROW;
        float4* v0 = reinterpret_cast<float4*>(dst0);
        v0[0] = make_float4(acc0[0].x, acc0[0].y, acc0[1].x, acc0[1].y);
        v0[1] = make_float4(acc0[2].x, acc0[2].y, acc0[3].x, acc0[3].y);
        v0[2] = make_float4(acc0[4].x, acc0[4].y, acc0[5].x, acc0[5].y);
        v0[3] = make_float4(acc0[6].x, acc0[6].y, acc0[7].x, acc0[7].y);
        v0[4] = make_float4(acc0[8].x, acc0[8].y, acc0[9].y, 0.f);   // [18]=den

        float* dst1 = pp + ((size_t)(b*CHUNKS + chunk)*MM + mlo + 128)*PROW;
        float4* v1 = reinterpret_cast<float4*>(dst1);
        v1[0] = make_float4(acc1[0].x, acc1[0].y, acc1[1].x, acc1[1].y);
        v1[1] = make_float4(acc1[2].x, acc1[2].y, acc1[3].x, acc1[3].y);
        v1[2] = make_float4(acc1[4].x, acc1[4].y, acc1[5].x, acc1[5].y);
        v1[3] = make_float4(acc1[6].x, acc1[6].y, acc1[7].x, acc1[7].y);
        v1[4] = make_float4(acc1[8].x, acc1[8].y, acc1[9].y, 0.f);
    }
}

// ---------------------------------------------------------------------------
// Final iteration kernel — MFMA (bf16-split) distance + register softmax.
// Wave wv owns m in [64wv, 64wv+64) as 8 B-fragments (hi/lo x 4 m-tiles,
// built once). Per 16-px n-tile: A-fragments built on the fly from the fp32
// pls rows (8 floats -> bf16 hi/lo), 3 MFMAs per 16x16 tile
// (hi*hi + hi*lo + lo*hi ~ fp32-accurate dot; padding k>=18 zeroed on B).
// D layout (HW-verified m89): col=lane&15 (m), row=(lane>>4)*4+reg (px).
// Softmax: 16-lane butterfly (sums the wave's 64 m) + cross-wave LDS combine.
// ---------------------------------------------------------------------------
__global__ __launch_bounds__(256, 3)
void ssn_fin(const float* __restrict__ ptbuf, const float* __restrict__ cbuf,
             float* __restrict__ qout)
{
    __shared__ __align__(16) float pls[PIXPERBLK*PROW];   // 10240 B
    __shared__ float ssum_s[4][32];
    __shared__ float w_s[32];

    const int tid    = threadIdx.x;
    const int b      = blockIdx.x >> 9;
    const int chunk  = blockIdx.x & (CHUNKS-1);
    const int n_base = chunk * PIXPERBLK;
    const int L      = tid & 63;
    const int wv     = tid >> 6;
    const int g      = L >> 4;      // k-group 0..3 (k = 8g+j nominal)
    const int al     = L & 15;      // A-row (px) / B-col (m) index

    // stage 128 rows x 80 B, fully coalesced
    {
        const float4* src = reinterpret_cast<const float4*>(
            ptbuf + (size_t)(b*NN + n_base)*PROW);
#pragma unroll
        for (int k = 0; k < 3; ++k) {
            int f = tid + (k << 8);
            if (f < PIXPERBLK*PROW/4)
                reinterpret_cast<float4*>(pls)[f] = src[f];
        }
    }

    // ---- B fragments (centers) + cn2, built once ----
    bf16x8 bhi[4], blo[4]; float cn2m[4];
#pragma unroll
    for (int mt = 0; mt < 4; ++mt) {
        const float* crow = cbuf + (size_t)(b*MM + wv*64 + mt*16 + al)*CROW;
        float bf_[8];
#pragma unroll
        for (int j = 0; j < 8; ++j) bf_[j] = 0.f;
        if (g < 2) {
            float4 c0 = *reinterpret_cast<const float4*>(crow + 8*g);
            float4 c1 = *reinterpret_cast<const float4*>(crow + 8*g + 4);
            bf_[0]=c0.x; bf_[1]=c0.y; bf_[2]=c0.z; bf_[3]=c0.w;
            bf_[4]=c1.x; bf_[5]=c1.y; bf_[6]=c1.z; bf_[7]=c1.w;
        } else if (g == 2) {
            float4 c0 = *reinterpret_cast<const float4*>(crow + 16);
            bf_[0]=c0.x; bf_[1]=c0.y;      // k=16,17 (x,y); k>=18 stays 0
        }
#pragma unroll
        for (int j = 0; j < 8; ++j) {
            unsigned short h = f2bf(bf_[j]);
            bhi[mt][j] = (short)h;
            blo[mt][j] = (short)f2bf(bf_[j] - bf2f(h));
        }
        cn2m[mt] = crow[18];
    }

    __syncthreads();   // pls ready

#pragma unroll
    for (int pair = 0; pair < 4; ++pair) {
        float e[2][4][4];
        float part[2][4];

#pragma unroll
        for (int h = 0; h < 2; ++h) {
            const int pxt = pair*32 + h*16;     // n-tile base within block

            // ---- A fragment (pixels) from fp32 LDS rows ----
            float af[8];
#pragma unroll
            for (int j = 0; j < 8; ++j) af[j] = 0.f;
            const int abase = (pxt + al)*PROW;
            if (g < 2) {
                float4 x0 = *reinterpret_cast<const float4*>(&pls[abase + 8*g]);
                float4 x1 = *reinterpret_cast<const float4*>(&pls[abase + 8*g + 4]);
                af[0]=x0.x; af[1]=x0.y; af[2]=x0.z; af[3]=x0.w;
                af[4]=x1.x; af[5]=x1.y; af[6]=x1.z; af[7]=x1.w;
            } else if (g == 2) {
                float4 x0 = *reinterpret_cast<const float4*>(&pls[abase + 16]);
                af[0]=x0.x; af[1]=x0.y;          // k=16,17; k>=18 zero (B is 0 there anyway)
            }
            bf16x8 ahi, alo;
#pragma unroll
            for (int j = 0; j < 8; ++j) {
                unsigned short hb = f2bf(af[j]);
                ahi[j] = (short)hb;
                alo[j] = (short)f2bf(af[j] - bf2f(hb));
            }

            // pn2 for this lane's 4 output rows (px = pxt + 4g + r)
            float pn2v[4];
#pragma unroll
            for (int r = 0; r < 4; ++r)
                pn2v[r] = pls[(pxt + 4*g + r)*PROW + 18];

#pragma unroll
            for (int mt = 0; mt < 4; ++mt) {
                f32x4v dt = {0.f, 0.f, 0.f, 0.f};
                dt = __builtin_amdgcn_mfma_f32_16x16x32_bf16(ahi, bhi[mt], dt, 0, 0, 0);
                dt = __builtin_amdgcn_mfma_f32_16x16x32_bf16(ahi, blo[mt], dt, 0, 0, 0);
                dt = __builtin_amdgcn_mfma_f32_16x16x32_bf16(alo, bhi[mt], dt, 0, 0, 0);
#pragma unroll
                for (int r = 0; r < 4; ++r) {
                    float d2 = fmaf(-2.f, dt[r], pn2v[r] + cn2m[mt]);
                    e[h][mt][r] = __expf(-__builtin_amdgcn_sqrtf(fmaxf(d2, 1e-12f)));
                }
            }
#pragma unroll
            for (int r = 0; r < 4; ++r)
                part[h][r] = (e[h][0][r] + e[h][1][r]) + (e[h][2][r] + e[h][3][r]);
        }

        // 16-lane butterfly: sum over the wave's 64 m per px row
#pragma unroll
        for (int mask = 1; mask <= 8; mask <<= 1) {
#pragma unroll
            for (int h = 0; h < 2; ++h)
#pragma unroll
                for (int r = 0; r < 4; ++r)
                    part[h][r] += __shfl_xor(part[h][r], mask);
        }
        if (al == 0) {
#pragma unroll
            for (int h = 0; h < 2; ++h)
#pragma unroll
                for (int r = 0; r < 4; ++r)
                    ssum_s[wv][h*16 + 4*g + r] = part[h][r];
        }
        __syncthreads();
        if (tid < 32)
            w_s[tid] = 1.0f / (ssum_s[0][tid] + ssum_s[1][tid]
                             + ssum_s[2][tid] + ssum_s[3][tid]);
        __syncthreads();

        // Q stores: px = pair*32 + h*16 + 4g + r ; m = wv*64 + mt*16 + al
#pragma unroll
        for (int h = 0; h < 2; ++h) {
#pragma unroll
            for (int r = 0; r < 4; ++r) {
                const float w = w_s[h*16 + 4*g + r];
                const size_t rowoff =
                    ((size_t)(b*NN + n_base + pair*32 + h*16 + 4*g + r)) << 8;
#pragma unroll
                for (int mt = 0; mt < 4; ++mt)
                    qout[rowoff + wv*64 + mt*16 + al] = e[h][mt][r] * w;
            }
        }
    }
}

// ---------------------------------------------------------------------------
// Sum the 512 per-chunk partials for each (b,m); produce new centers row
// (c, ||c||^2) and optionally centers_feat. block=(b,m), thread=chunk low 8b.
// ---------------------------------------------------------------------------
__global__ __launch_bounds__(256)
void reduce_finalize(const float* __restrict__ pp, float* __restrict__ cbuf,
                     float* __restrict__ cfout, int write_cf)
{
    const int b   = blockIdx.x >> 8;
    const int m   = blockIdx.x & 255;
    const int tid = threadIdx.x;
    const int lane = tid & 63, wv = tid >> 6;

    const float4* r0 = reinterpret_cast<const float4*>(
        pp + ((size_t)(b*CHUNKS + tid)*MM + m)*PROW);
    const float4* r1 = reinterpret_cast<const float4*>(
        pp + ((size_t)(b*CHUNKS + tid + 256)*MM + m)*PROW);
    float a[19];
    {
        float4 u0=r0[0], u1=r0[1], u2=r0[2], u3=r0[3], u4=r0[4];
        float4 w0=r1[0], w1=r1[1], w2=r1[2], w3=r1[3], w4=r1[4];
        a[0]=u0.x+w0.x;  a[1]=u0.y+w0.y;  a[2]=u0.z+w0.z;  a[3]=u0.w+w0.w;
        a[4]=u1.x+w1.x;  a[5]=u1.y+w1.y;  a[6]=u1.z+w1.z;  a[7]=u1.w+w1.w;
        a[8]=u2.x+w2.x;  a[9]=u2.y+w2.y;  a[10]=u2.z+w2.z; a[11]=u2.w+w2.w;
        a[12]=u3.x+w3.x; a[13]=u3.y+w3.y; a[14]=u3.z+w3.z; a[15]=u3.w+w3.w;
        a[16]=u4.x+w4.x; a[17]=u4.y+w4.y; a[18]=u4.z+w4.z;
    }
#pragma unroll
    for (int off = 32; off; off >>= 1) {
#pragma unroll
        for (int d = 0; d < 19; ++d) a[d] += __shfl_down(a[d], off);
    }

    __shared__ float red[4][20];
    if (lane == 0) {
#pragma unroll
        for (int d = 0; d < 19; ++d) red[wv][d] = a[d];
    }
    __syncthreads();
    if (tid == 0) {
        float s[19];
#pragma unroll
        for (int d = 0; d < 19; ++d)
            s[d] = red[0][d] + red[1][d] + red[2][d] + red[3][d];
        float den = s[18] + 1e-6f;
        float* row = cbuf + (b*MM + m)*CROW;
        float cn2 = 0.f;
#pragma unroll
        for (int d = 0; d < 18; ++d) {
            float cv = s[d] / den;
            row[d] = cv;
            cn2 = fmaf(cv, cv, cn2);
            if (write_cf && d < 16) cfout[((b*CC + d) << 8) + m] = cv;
        }
        row[18] = cn2;
        row[19] = 0.f;
    }
}

// ---------------------------------------------------------------------------
extern "C" void kernel_launch(void* const* d_in, const int* in_sizes, int n_in,
                              void* d_out, int out_size, void* d_ws, size_t ws_size,
                              hipStream_t stream)
{
    const float* feat = (const float*)d_in[0];
    float* dout = (float*)d_out;

    // d_ws layout: cbuf (128 KB) | ptbuf 21 MB | pp 42 MB
    float* cbuf  = (float*)d_ws;
    float* ptbuf = cbuf + 32768;
    float* pp    = ptbuf + (size_t)BB*NN*PROW;

    float* qout  = dout;                                // [B, N, M]
    float* cfout = dout + (size_t)BB*NN*MM;             // [B, C, M]

    build_pt<<<dim3(BB*256), dim3(256), 0, stream>>>(feat, ptbuf);
    init_centers<<<dim3(BB*MM), dim3(64), 0, stream>>>(feat, cbuf);

    for (int it = 0; it < 2; ++it) {
        ssn_nf<<<dim3(BB*CHUNKS), dim3(256), 0, stream>>>(ptbuf, cbuf, pp);
        reduce_finalize<<<dim3(BB*MM), dim3(256), 0, stream>>>(pp, cbuf, cfout, it == 1);
    }
    ssn_fin<<<dim3(BB*CHUNKS), dim3(256), 0, stream>>>(ptbuf, cbuf, qout);
}

// Round 16
// 251.354 us; speedup vs baseline: 1.0947x; 1.0947x over previous
//
#include <hip/hip_runtime.h>
#include <math.h>

// Problem constants (B,C,H,W fixed by the reference)
#define BB 4
#define CC 16
#define HH 256
#define WW 256
#define NN (HH*WW)        // 65536 pixels per batch
#define MM 256            // superpixels
#define CROW 20           // padded center row: c[0..17], [18]=||c||^2, [19]=pad
#define PROW 20           // pixel row: p[0..17], [18]=||p||^2, [19]=1.0
#define PIX 32            // pixels per sub-tile
#define TSUB 4            // sub-tiles per block (128 px/block)
#define PIXPERBLK (PIX*TSUB)
#define CHUNKS (NN/PIXPERBLK)   // 512 chunks per batch

typedef float f32x2 __attribute__((ext_vector_type(2)));
typedef float f32x4v __attribute__((ext_vector_type(4)));
typedef short bf16x8 __attribute__((ext_vector_type(8)));

__device__ __forceinline__ f32x2 mk2(float a, float b) { f32x2 r; r.x = a; r.y = b; return r; }
__device__ __forceinline__ f32x2 pk_fma(f32x2 a, f32x2 b, f32x2 c) {
    return __builtin_elementwise_fma(a, b, c);
}

// fp32 -> bf16 bits (RNE) and back, via bit ops
__device__ __forceinline__ unsigned short f2bf(float f) {
    unsigned u = __builtin_bit_cast(unsigned, f);
    unsigned r = (u + 0x7FFFu + ((u >> 16) & 1u)) >> 16;
    return (unsigned short)r;
}
__device__ __forceinline__ float bf2f(unsigned short v) {
    unsigned u = ((unsigned)v) << 16;
    return __builtin_bit_cast(float, u);
}

// ---------------------------------------------------------------------------
// Initial centers: 16x16 block means of features + analytic xy means + ||c||^2
// ---------------------------------------------------------------------------
__global__ void init_centers(const float* __restrict__ feat, float* __restrict__ cbuf)
{
    const int b    = blockIdx.x >> 8;
    const int m    = blockIdx.x & 255;
    const int lane = threadIdx.x;          // 0..63
    const int sy = m >> 4, sx = m & 15;

    float cvals[16];
#pragma unroll
    for (int d = 0; d < 16; ++d) {
        float v = 0.f;
#pragma unroll
        for (int k = 0; k < 4; ++k) {
            int q  = lane + (k << 6);            // 0..255 within 16x16 block
            int py = q >> 4, px = q & 15;
            int n  = (sy*16 + py)*WW + sx*16 + px;
            v += feat[((b*CC + d) << 16) + n];
        }
#pragma unroll
        for (int off = 32; off; off >>= 1) v += __shfl_down(v, off);
        cvals[d] = v * (1.f/256.f);
    }
    if (lane == 0) {
        float* row = cbuf + (b*MM + m)*CROW;
        float cn2 = 0.f;
#pragma unroll
        for (int d = 0; d < 16; ++d) { row[d] = cvals[d]; cn2 = fmaf(cvals[d], cvals[d], cn2); }
        float cx = (sx*16 + 7.5f) * (1.f/256.f);
        float cy = (sy*16 + 7.5f) * (1.f/256.f);
        row[16] = cx; row[17] = cy;
        cn2 = fmaf(cx, cx, cn2);
        cn2 = fmaf(cy, cy, cn2);
        row[18] = cn2;
        row[19] = 0.f;
    }
}

// ---------------------------------------------------------------------------
// Pre-transpose: pixel rows {p[0..17], ||p||^2, 1.0} into contiguous
// ptbuf[b][n][20] in d_ws.
// ---------------------------------------------------------------------------
__global__ void build_pt(const float* __restrict__ feat, float* __restrict__ ptbuf)
{
    const int b = blockIdx.x >> 8;
    const int n = ((blockIdx.x & 255) << 8) | threadIdx.x;
    float v[16];
#pragma unroll
    for (int d = 0; d < 16; ++d) v[d] = feat[((b*CC + d) << 16) + n];
    float x = (float)(n & 255) * (1.f/256.f);
    float y = (float)(n >> 8) * (1.f/256.f);
    float pn2 = 0.f;
#pragma unroll
    for (int d = 0; d < 16; ++d) pn2 = fmaf(v[d], v[d], pn2);
    pn2 = fmaf(x, x, pn2);
    pn2 = fmaf(y, y, pn2);
    float4* row = reinterpret_cast<float4*>(ptbuf + (size_t)(b*NN + n)*PROW);
    row[0] = make_float4(v[0],  v[1],  v[2],  v[3]);
    row[1] = make_float4(v[4],  v[5],  v[6],  v[7]);
    row[2] = make_float4(v[8],  v[9],  v[10], v[11]);
    row[3] = make_float4(v[12], v[13], v[14], v[15]);
    row[4] = make_float4(x, y, pn2, 1.0f);
}

// ---------------------------------------------------------------------------
// Non-final iteration kernel — FULL MFMA (bf16-split, 3-term).
// Wave wv owns m in [64wv, 64wv+64) (4 m-tiles, col = lane&15).
// Per 32-px pair (2 stacked 16-px tiles = one K=32 step):
//   phase 1: D1[px][m] via 3 MFMAs/tile (f-invariant packing, proven r15);
//            e[h][mt][r] for px = pxt + h*16 + 4g + r (m89 D layout).
//   softmax: 16-lane butterfly + cross-wave LDS combine (2 barriers).
//   phase 2: pp[m][d] += ew·p via MFMA. KEY: under the measured k-map
//            k = 4g+j (j<4) / 16+4g+(j-4) (j>=4)  [m156 tr-read layout],
//            the two tiles' D-rows ARE the A-fragment of ew for K=32 —
//            zero shuffles. B = p columns (8 scalar LDS reads, 2-way-free).
//            den accumulates via p[.][19]=1.0 column -> pp slot 19.
// No partner combine: MFMA accumulates all 128 px into acc directly.
// ---------------------------------------------------------------------------
__global__ __launch_bounds__(256, 3)
void ssn_nf(const float* __restrict__ ptbuf, const float* __restrict__ cbuf,
            float* __restrict__ pp)
{
    __shared__ __align__(16) float pls[PIXPERBLK*PROW];   // 10240 B
    __shared__ float ssum_s[4][32];
    __shared__ float w_s[32];

    const int tid    = threadIdx.x;
    const int b      = blockIdx.x >> 9;
    const int chunk  = blockIdx.x & (CHUNKS-1);
    const int n_base = chunk * PIXPERBLK;
    const int L      = tid & 63;
    const int wv     = tid >> 6;
    const int g      = L >> 4;      // lane group 0..3
    const int al     = L & 15;      // A-row / B-col index

    // stage 128 rows x 80 B, fully coalesced
    {
        const float4* src = reinterpret_cast<const float4*>(
            ptbuf + (size_t)(b*NN + n_base)*PROW);
#pragma unroll
        for (int k = 0; k < 3; ++k) {
            int f = tid + (k << 8);
            if (f < PIXPERBLK*PROW/4)
                reinterpret_cast<float4*>(pls)[f] = src[f];
        }
    }

    // ---- center B fragments + cn2 (f-invariant packing, same as r15) ----
    bf16x8 bhi[4], blo[4]; float cn2m[4];
#pragma unroll
    for (int mt = 0; mt < 4; ++mt) {
        const float* crow = cbuf + (size_t)(b*MM + wv*64 + mt*16 + al)*CROW;
        float bf_[8];
#pragma unroll
        for (int j = 0; j < 8; ++j) bf_[j] = 0.f;
        if (g < 2) {
            float4 c0 = *reinterpret_cast<const float4*>(crow + 8*g);
            float4 c1 = *reinterpret_cast<const float4*>(crow + 8*g + 4);
            bf_[0]=c0.x; bf_[1]=c0.y; bf_[2]=c0.z; bf_[3]=c0.w;
            bf_[4]=c1.x; bf_[5]=c1.y; bf_[6]=c1.z; bf_[7]=c1.w;
        } else if (g == 2) {
            float4 c0 = *reinterpret_cast<const float4*>(crow + 16);
            bf_[0]=c0.x; bf_[1]=c0.y;
        }
#pragma unroll
        for (int j = 0; j < 8; ++j) {
            unsigned short h = f2bf(bf_[j]);
            bhi[mt][j] = (short)h;
            blo[mt][j] = (short)f2bf(bf_[j] - bf2f(h));
        }
        cn2m[mt] = crow[18];
    }

    // phase-2 accumulators: accA = d 0..15, accB = d 16..19 (19 = den)
    f32x4v accA[4], accB[4];
#pragma unroll
    for (int mt = 0; mt < 4; ++mt) {
        accA[mt] = (f32x4v){0.f,0.f,0.f,0.f};
        accB[mt] = (f32x4v){0.f,0.f,0.f,0.f};
    }

    __syncthreads();   // pls ready

#pragma unroll
    for (int pair = 0; pair < 4; ++pair) {
        const int pxt = pair*32;
        float e[2][4][4];
        float part[2][4];

        // ---- phase 1: two 16-px tiles ----
#pragma unroll
        for (int h = 0; h < 2; ++h) {
            const int pxb = pxt + h*16;
            float af[8];
#pragma unroll
            for (int j = 0; j < 8; ++j) af[j] = 0.f;
            const int abase = (pxb + al)*PROW;
            if (g < 2) {
                float4 x0 = *reinterpret_cast<const float4*>(&pls[abase + 8*g]);
                float4 x1 = *reinterpret_cast<const float4*>(&pls[abase + 8*g + 4]);
                af[0]=x0.x; af[1]=x0.y; af[2]=x0.z; af[3]=x0.w;
                af[4]=x1.x; af[5]=x1.y; af[6]=x1.z; af[7]=x1.w;
            } else if (g == 2) {
                float4 x0 = *reinterpret_cast<const float4*>(&pls[abase + 16]);
                af[0]=x0.x; af[1]=x0.y;
            }
            bf16x8 ahi, alo;
#pragma unroll
            for (int j = 0; j < 8; ++j) {
                unsigned short hb = f2bf(af[j]);
                ahi[j] = (short)hb;
                alo[j] = (short)f2bf(af[j] - bf2f(hb));
            }

            float pn2v[4];
#pragma unroll
            for (int r = 0; r < 4; ++r)
                pn2v[r] = pls[(pxb + 4*g + r)*PROW + 18];

#pragma unroll
            for (int mt = 0; mt < 4; ++mt) {
                f32x4v dt = {0.f, 0.f, 0.f, 0.f};
                dt = __builtin_amdgcn_mfma_f32_16x16x32_bf16(ahi, bhi[mt], dt, 0, 0, 0);
                dt = __builtin_amdgcn_mfma_f32_16x16x32_bf16(ahi, blo[mt], dt, 0, 0, 0);
                dt = __builtin_amdgcn_mfma_f32_16x16x32_bf16(alo, bhi[mt], dt, 0, 0, 0);
#pragma unroll
                for (int r = 0; r < 4; ++r) {
                    float d2 = fmaf(-2.f, dt[r], pn2v[r] + cn2m[mt]);
                    e[h][mt][r] = __expf(-__builtin_amdgcn_sqrtf(fmaxf(d2, 1e-12f)));
                }
            }
#pragma unroll
            for (int r = 0; r < 4; ++r)
                part[h][r] = (e[h][0][r] + e[h][1][r]) + (e[h][2][r] + e[h][3][r]);
        }

        // ---- softmax denominator: butterfly over al + cross-wave combine ----
#pragma unroll
        for (int mask = 1; mask <= 8; mask <<= 1) {
#pragma unroll
            for (int h = 0; h < 2; ++h)
#pragma unroll
                for (int r = 0; r < 4; ++r)
                    part[h][r] += __shfl_xor(part[h][r], mask);
        }
        if (al == 0) {
#pragma unroll
            for (int h = 0; h < 2; ++h)
#pragma unroll
                for (int r = 0; r < 4; ++r)
                    ssum_s[wv][h*16 + 4*g + r] = part[h][r];
        }
        __syncthreads();
        if (tid < 32)
            w_s[tid] = 1.0f / (ssum_s[0][tid] + ssum_s[1][tid]
                             + ssum_s[2][tid] + ssum_s[3][tid]);
        __syncthreads();

        // ---- phase 2: pp += ew · p  (one K=32 MFMA step over this pair) ----
        float w0[4], w1[4];
#pragma unroll
        for (int r = 0; r < 4; ++r) {
            w0[r] = w_s[4*g + r];
            w1[r] = w_s[16 + 4*g + r];
        }

        // B fragments: p columns at px = pxt + k, k-map k=4g+j / 16+4g+(j-4)
        bf16x8 p0h, p0l, p1h, p1l;
#pragma unroll
        for (int j = 0; j < 8; ++j) {
            const int px = pxt + ((j < 4) ? (4*g + j) : (16 + 4*g + (j-4)));
            float f0 = pls[px*PROW + al];
            unsigned short h0 = f2bf(f0);
            p0h[j] = (short)h0;
            p0l[j] = (short)f2bf(f0 - bf2f(h0));
            float f1 = (al < 4) ? pls[px*PROW + 16 + al] : 0.f;
            unsigned short h1 = f2bf(f1);
            p1h[j] = (short)h1;
            p1l[j] = (short)f2bf(f1 - bf2f(h1));
        }

#pragma unroll
        for (int mt = 0; mt < 4; ++mt) {
            // A fragment: ew for k-map px slots — phase-1 D rows align exactly
            bf16x8 awh, awl;
#pragma unroll
            for (int j = 0; j < 8; ++j) {
                float ev = (j < 4) ? e[0][mt][j] * w0[j]
                                   : e[1][mt][j-4] * w1[j-4];
                unsigned short hh = f2bf(ev);
                awh[j] = (short)hh;
                awl[j] = (short)f2bf(ev - bf2f(hh));
            }
            accA[mt] = __builtin_amdgcn_mfma_f32_16x16x32_bf16(awh, p0h, accA[mt], 0, 0, 0);
            accA[mt] = __builtin_amdgcn_mfma_f32_16x16x32_bf16(awh, p0l, accA[mt], 0, 0, 0);
            accA[mt] = __builtin_amdgcn_mfma_f32_16x16x32_bf16(awl, p0h, accA[mt], 0, 0, 0);
            accB[mt] = __builtin_amdgcn_mfma_f32_16x16x32_bf16(awh, p1h, accB[mt], 0, 0, 0);
            accB[mt] = __builtin_amdgcn_mfma_f32_16x16x32_bf16(awh, p1l, accB[mt], 0, 0, 0);
            accB[mt] = __builtin_amdgcn_mfma_f32_16x16x32_bf16(awl, p1h, accB[mt], 0, 0, 0);
        }
    }

    // ---- store pp: D layout row = 4g+reg (m within tile), col = al (d) ----
#pragma unroll
    for (int mt = 0; mt < 4; ++mt) {
#pragma unroll
        for (int r = 0; r < 4; ++r) {
            const int m = wv*64 + mt*16 + 4*g + r;
            float* dst = pp + ((size_t)(b*CHUNKS + chunk)*MM + m)*PROW;
            dst[al] = accA[mt][r];                 // d = 0..15
            if (al < 4) dst[16 + al] = accB[mt][r]; // d = 16..19 (19 = den)
        }
    }
}

// ---------------------------------------------------------------------------
// Final iteration kernel — barrier-free KM=4 VALU (best-measured, r14).
// ---------------------------------------------------------------------------
__device__ __forceinline__ void rowdot4(const float* __restrict__ prow,
                                        const f32x2 (&cp)[4][9], const float (&cn2)[4],
                                        float (&e)[4])
{
    const float4* pv = reinterpret_cast<const float4*>(prow);
    float4 q0 = pv[0], q1 = pv[1], q2 = pv[2], q3 = pv[3], q4 = pv[4];
    f32x2 u[9];
    u[0]=mk2(q0.x,q0.y); u[1]=mk2(q0.z,q0.w); u[2]=mk2(q1.x,q1.y);
    u[3]=mk2(q1.z,q1.w); u[4]=mk2(q2.x,q2.y); u[5]=mk2(q2.z,q2.w);
    u[6]=mk2(q3.x,q3.y); u[7]=mk2(q3.z,q3.w); u[8]=mk2(q4.x,q4.y);
    f32x2 d0=mk2(0.f,0.f), d1=mk2(0.f,0.f), d2=mk2(0.f,0.f), d3=mk2(0.f,0.f);
#pragma unroll
    for (int i = 0; i < 9; ++i) {
        d0 = pk_fma(u[i], cp[0][i], d0);
        d1 = pk_fma(u[i], cp[1][i], d1);
        d2 = pk_fma(u[i], cp[2][i], d2);
        d3 = pk_fma(u[i], cp[3][i], d3);
    }
    float s0 = fmaf(-2.f, d0.x + d0.y, q4.z + cn2[0]);
    float s1 = fmaf(-2.f, d1.x + d1.y, q4.z + cn2[1]);
    float s2 = fmaf(-2.f, d2.x + d2.y, q4.z + cn2[2]);
    float s3 = fmaf(-2.f, d3.x + d3.y, q4.z + cn2[3]);
    e[0] = __expf(-__builtin_amdgcn_sqrtf(fmaxf(s0, 1e-12f)));
    e[1] = __expf(-__builtin_amdgcn_sqrtf(fmaxf(s1, 1e-12f)));
    e[2] = __expf(-__builtin_amdgcn_sqrtf(fmaxf(s2, 1e-12f)));
    e[3] = __expf(-__builtin_amdgcn_sqrtf(fmaxf(s3, 1e-12f)));
}

#define RS8(L, s) \
    { const bool hi = ((L) & 1); \
      _Pragma("unroll") for (int k = 0; k < 4; ++k) { \
        float a = s[k], bq = s[k+4]; \
        float recv = __shfl_xor(hi ? a : bq, 1); \
        s[k] = (hi ? bq : a) + recv; } } \
    { const bool hi = ((L) & 2); \
      _Pragma("unroll") for (int k = 0; k < 2; ++k) { \
        float a = s[k], bq = s[k+2]; \
        float recv = __shfl_xor(hi ? a : bq, 2); \
        s[k] = (hi ? bq : a) + recv; } } \
    { const bool hi = ((L) & 4); \
      { float a = s[0], bq = s[1]; \
        float recv = __shfl_xor(hi ? a : bq, 4); \
        s[0] = (hi ? bq : a) + recv; } } \
    s[0] += __shfl_xor(s[0], 8); \
    s[0] += __shfl_xor(s[0], 16); \
    s[0] += __shfl_xor(s[0], 32);

__global__ __launch_bounds__(256, 3)
void ssn_fin(const float* __restrict__ ptbuf, const float* __restrict__ cbuf,
             float* __restrict__ qout)
{
    __shared__ __align__(16) float pls[PIXPERBLK*PROW];   // 10240 B

    const int tid    = threadIdx.x;
    const int b      = blockIdx.x >> 9;
    const int chunk  = blockIdx.x & (CHUNKS-1);
    const int n_base = chunk * PIXPERBLK;
    const int L      = tid & 63;
    const int wv     = tid >> 6;

    {
        const float4* src = reinterpret_cast<const float4*>(
            ptbuf + (size_t)(b*NN + n_base)*PROW);
#pragma unroll
        for (int k = 0; k < 3; ++k) {
            int f = tid + (k << 8);
            if (f < PIXPERBLK*PROW/4)
                reinterpret_cast<float4*>(pls)[f] = src[f];
        }
    }

    // centers m = 4L + j  (lane-contiguous -> float4 Q store)
    f32x2 cp[4][9]; float cn2[4];
#pragma unroll
    for (int j = 0; j < 4; ++j) {
        const float4* cv = reinterpret_cast<const float4*>(
            cbuf + (b*MM + 4*L + j)*CROW);
        float4 a0 = cv[0], a1 = cv[1], a2 = cv[2], a3 = cv[3], a4 = cv[4];
        cp[j][0]=mk2(a0.x,a0.y); cp[j][1]=mk2(a0.z,a0.w);
        cp[j][2]=mk2(a1.x,a1.y); cp[j][3]=mk2(a1.z,a1.w);
        cp[j][4]=mk2(a2.x,a2.y); cp[j][5]=mk2(a2.z,a2.w);
        cp[j][6]=mk2(a3.x,a3.y); cp[j][7]=mk2(a3.z,a3.w);
        cp[j][8]=mk2(a4.x,a4.y); cn2[j]=a4.z;
    }

    __syncthreads();   // pls ready

    for (int t = 0; t < TSUB; ++t) {
        const int pxb = t*PIX + wv*8;

        float e[4][8];
        float s[8];
#pragma unroll
        for (int k = 0; k < 8; ++k) {
            float ek[4];
            rowdot4(&pls[(pxb + k)*PROW], cp, cn2, ek);
            e[0][k] = ek[0]; e[1][k] = ek[1]; e[2][k] = ek[2]; e[3][k] = ek[3];
            s[k] = (ek[0] + ek[1]) + (ek[2] + ek[3]);
        }

        RS8(L, s)
        float wr = 1.0f / s[0];
        float w[8];
#pragma unroll
        for (int k = 0; k < 8; ++k)
            w[k] = __shfl(wr, ((k&1)<<2) | (k&2) | ((k>>2)&1));

#pragma unroll
        for (int k = 0; k < 8; ++k) {
            size_t rowoff = ((size_t)(b*NN + n_base + pxb + k)) << 8;
            float4 qv = make_float4(e[0][k]*w[k], e[1][k]*w[k],
                                    e[2][k]*w[k], e[3][k]*w[k]);
            *reinterpret_cast<float4*>(qout + rowoff + 4*L) = qv;
        }
    }
}

// ---------------------------------------------------------------------------
// Sum the 512 per-chunk partials for each (b,m); produce new centers row.
// pp layout: slots 0..17 = num, 18 = junk (Sum ew*pn2), 19 = den.
// ---------------------------------------------------------------------------
__global__ __launch_bounds__(256)
void reduce_finalize(const float* __restrict__ pp, float* __restrict__ cbuf,
                     float* __restrict__ cfout, int write_cf)
{
    const int b   = blockIdx.x >> 8;
    const int m   = blockIdx.x & 255;
    const int tid = threadIdx.x;
    const int lane = tid & 63, wv = tid >> 6;

    const float4* r0 = reinterpret_cast<const float4*>(
        pp + ((size_t)(b*CHUNKS + tid)*MM + m)*PROW);
    const float4* r1 = reinterpret_cast<const float4*>(
        pp + ((size_t)(b*CHUNKS + tid + 256)*MM + m)*PROW);
    float a[20];
    {
        float4 u0=r0[0], u1=r0[1], u2=r0[2], u3=r0[3], u4=r0[4];
        float4 w0=r1[0], w1=r1[1], w2=r1[2], w3=r1[3], w4=r1[4];
        a[0]=u0.x+w0.x;  a[1]=u0.y+w0.y;  a[2]=u0.z+w0.z;  a[3]=u0.w+w0.w;
        a[4]=u1.x+w1.x;  a[5]=u1.y+w1.y;  a[6]=u1.z+w1.z;  a[7]=u1.w+w1.w;
        a[8]=u2.x+w2.x;  a[9]=u2.y+w2.y;  a[10]=u2.z+w2.z; a[11]=u2.w+w2.w;
        a[12]=u3.x+w3.x; a[13]=u3.y+w3.y; a[14]=u3.z+w3.z; a[15]=u3.w+w3.w;
        a[16]=u4.x+w4.x; a[17]=u4.y+w4.y; a[18]=u4.z+w4.z; a[19]=u4.w+w4.w;
    }
#pragma unroll
    for (int off = 32; off; off >>= 1) {
#pragma unroll
        for (int d = 0; d < 20; ++d) a[d] += __shfl_down(a[d], off);
    }

    __shared__ float red[4][20];
    if (lane == 0) {
#pragma unroll
        for (int d = 0; d < 20; ++d) red[wv][d] = a[d];
    }
    __syncthreads();
    if (tid == 0) {
        float s[20];
#pragma unroll
        for (int d = 0; d < 20; ++d)
            s[d] = red[0][d] + red[1][d] + red[2][d] + red[3][d];
        float den = s[19] + 1e-6f;
        float* row = cbuf + (b*MM + m)*CROW;
        float cn2 = 0.f;
#pragma unroll
        for (int d = 0; d < 18; ++d) {
            float cv = s[d] / den;
            row[d] = cv;
            cn2 = fmaf(cv, cv, cn2);
            if (write_cf && d < 16) cfout[((b*CC + d) << 8) + m] = cv;
        }
        row[18] = cn2;
        row[19] = 0.f;
    }
}

// ---------------------------------------------------------------------------
extern "C" void kernel_launch(void* const* d_in, const int* in_sizes, int n_in,
                              void* d_out, int out_size, void* d_ws, size_t ws_size,
                              hipStream_t stream)
{
    const float* feat = (const float*)d_in[0];
    float* dout = (float*)d_out;

    // d_ws layout: cbuf (128 KB) | ptbuf 21 MB | pp 42 MB
    float* cbuf  = (float*)d_ws;
    float* ptbuf = cbuf + 32768;
    float* pp    = ptbuf + (size_t)BB*NN*PROW;

    float* qout  = dout;                                // [B, N, M]
    float* cfout = dout + (size_t)BB*NN*MM;             // [B, C, M]

    build_pt<<<dim3(BB*256), dim3(256), 0, stream>>>(feat, ptbuf);
    init_centers<<<dim3(BB*MM), dim3(64), 0, stream>>>(feat, cbuf);

    for (int it = 0; it < 2; ++it) {
        ssn_nf<<<dim3(BB*CHUNKS), dim3(256), 0, stream>>>(ptbuf, cbuf, pp);
        reduce_finalize<<<dim3(BB*MM), dim3(256), 0, stream>>>(pp, cbuf, cfout, it == 1);
    }
    ssn_fin<<<dim3(BB*CHUNKS), dim3(256), 0, stream>>>(ptbuf, cbuf, qout);
}

// Round 17
// 229.295 us; speedup vs baseline: 1.2000x; 1.0962x over previous
//
#include <hip/hip_runtime.h>
#include <hip/hip_bf16.h>
#include <math.h>

// Problem constants (B,C,H,W fixed by the reference)
#define BB 4
#define CC 16
#define HH 256
#define WW 256
#define NN (HH*WW)        // 65536 pixels per batch
#define MM 256            // superpixels
#define CROW 20           // padded center row: c[0..17], [18]=||c||^2, [19]=pad
#define PROW 20           // pixel row: p[0..17], [18]=||p||^2, [19]=1.0
#define PIX 32            // pixels per sub-tile
#define TSUB 4            // sub-tiles per block (128 px/block)
#define PIXPERBLK (PIX*TSUB)
#define CHUNKS (NN/PIXPERBLK)   // 512 chunks per batch

typedef float f32x2 __attribute__((ext_vector_type(2)));
typedef float f32x4v __attribute__((ext_vector_type(4)));
typedef short bf16x8 __attribute__((ext_vector_type(8)));

__device__ __forceinline__ f32x2 mk2(float a, float b) { f32x2 r; r.x = a; r.y = b; return r; }
__device__ __forceinline__ f32x2 pk_fma(f32x2 a, f32x2 b, f32x2 c) {
    return __builtin_elementwise_fma(a, b, c);
}

// Native bf16 conversion (compiler emits v_cvt_pk_bf16_f32 for pairs — m240:
// don't hand-write). hi = bf16(f); hif = float(hi); lo = bf16(f - hif).
__device__ __forceinline__ short bfhi(float f, float& hif) {
    __hip_bfloat16 h = __float2bfloat16(f);
    hif = __bfloat162float(h);
    return __builtin_bit_cast(short, h);
}
__device__ __forceinline__ short bflo(float f, float hif) {
    __hip_bfloat16 l = __float2bfloat16(f - hif);
    return __builtin_bit_cast(short, l);
}

// ---------------------------------------------------------------------------
// Initial centers: 16x16 block means of features + analytic xy means + ||c||^2
// ---------------------------------------------------------------------------
__global__ void init_centers(const float* __restrict__ feat, float* __restrict__ cbuf)
{
    const int b    = blockIdx.x >> 8;
    const int m    = blockIdx.x & 255;
    const int lane = threadIdx.x;          // 0..63
    const int sy = m >> 4, sx = m & 15;

    float cvals[16];
#pragma unroll
    for (int d = 0; d < 16; ++d) {
        float v = 0.f;
#pragma unroll
        for (int k = 0; k < 4; ++k) {
            int q  = lane + (k << 6);            // 0..255 within 16x16 block
            int py = q >> 4, px = q & 15;
            int n  = (sy*16 + py)*WW + sx*16 + px;
            v += feat[((b*CC + d) << 16) + n];
        }
#pragma unroll
        for (int off = 32; off; off >>= 1) v += __shfl_down(v, off);
        cvals[d] = v * (1.f/256.f);
    }
    if (lane == 0) {
        float* row = cbuf + (b*MM + m)*CROW;
        float cn2 = 0.f;
#pragma unroll
        for (int d = 0; d < 16; ++d) { row[d] = cvals[d]; cn2 = fmaf(cvals[d], cvals[d], cn2); }
        float cx = (sx*16 + 7.5f) * (1.f/256.f);
        float cy = (sy*16 + 7.5f) * (1.f/256.f);
        row[16] = cx; row[17] = cy;
        cn2 = fmaf(cx, cx, cn2);
        cn2 = fmaf(cy, cy, cn2);
        row[18] = cn2;
        row[19] = 0.f;
    }
}

// ---------------------------------------------------------------------------
// Pre-transpose: pixel rows {p[0..17], ||p||^2, 1.0} into contiguous
// ptbuf[b][n][20] in d_ws.
// ---------------------------------------------------------------------------
__global__ void build_pt(const float* __restrict__ feat, float* __restrict__ ptbuf)
{
    const int b = blockIdx.x >> 8;
    const int n = ((blockIdx.x & 255) << 8) | threadIdx.x;
    float v[16];
#pragma unroll
    for (int d = 0; d < 16; ++d) v[d] = feat[((b*CC + d) << 16) + n];
    float x = (float)(n & 255) * (1.f/256.f);
    float y = (float)(n >> 8) * (1.f/256.f);
    float pn2 = 0.f;
#pragma unroll
    for (int d = 0; d < 16; ++d) pn2 = fmaf(v[d], v[d], pn2);
    pn2 = fmaf(x, x, pn2);
    pn2 = fmaf(y, y, pn2);
    float4* row = reinterpret_cast<float4*>(ptbuf + (size_t)(b*NN + n)*PROW);
    row[0] = make_float4(v[0],  v[1],  v[2],  v[3]);
    row[1] = make_float4(v[4],  v[5],  v[6],  v[7]);
    row[2] = make_float4(v[8],  v[9],  v[10], v[11]);
    row[3] = make_float4(v[12], v[13], v[14], v[15]);
    row[4] = make_float4(x, y, pn2, 1.0f);
}

// ---------------------------------------------------------------------------
// Non-final iteration kernel — FULL MFMA (bf16-split, 3-term), native casts.
// Structure proven in r16 (absmax 3.05e-5): phase-1 f-invariant packing,
// phase-2 k-map-aligned A-fragment (D rows = A slots, zero shuffles),
// den via p[.][19]=1.0 column -> pp slot 19.
// ---------------------------------------------------------------------------
__global__ __launch_bounds__(256, 3)
void ssn_nf(const float* __restrict__ ptbuf, const float* __restrict__ cbuf,
            float* __restrict__ pp)
{
    __shared__ __align__(16) float pls[PIXPERBLK*PROW];   // 10240 B
    __shared__ float ssum_s[4][32];
    __shared__ float w_s[32];

    const int tid    = threadIdx.x;
    const int b      = blockIdx.x >> 9;
    const int chunk  = blockIdx.x & (CHUNKS-1);
    const int n_base = chunk * PIXPERBLK;
    const int L      = tid & 63;
    const int wv     = tid >> 6;
    const int g      = L >> 4;      // lane group 0..3
    const int al     = L & 15;      // A-row / B-col index

    // stage 128 rows x 80 B, fully coalesced
    {
        const float4* src = reinterpret_cast<const float4*>(
            ptbuf + (size_t)(b*NN + n_base)*PROW);
#pragma unroll
        for (int k = 0; k < 3; ++k) {
            int f = tid + (k << 8);
            if (f < PIXPERBLK*PROW/4)
                reinterpret_cast<float4*>(pls)[f] = src[f];
        }
    }

    // ---- center B fragments + cn2 (f-invariant packing) ----
    bf16x8 bhi[4], blo[4]; float cn2m[4];
#pragma unroll
    for (int mt = 0; mt < 4; ++mt) {
        const float* crow = cbuf + (size_t)(b*MM + wv*64 + mt*16 + al)*CROW;
        float bf_[8];
#pragma unroll
        for (int j = 0; j < 8; ++j) bf_[j] = 0.f;
        if (g < 2) {
            float4 c0 = *reinterpret_cast<const float4*>(crow + 8*g);
            float4 c1 = *reinterpret_cast<const float4*>(crow + 8*g + 4);
            bf_[0]=c0.x; bf_[1]=c0.y; bf_[2]=c0.z; bf_[3]=c0.w;
            bf_[4]=c1.x; bf_[5]=c1.y; bf_[6]=c1.z; bf_[7]=c1.w;
        } else if (g == 2) {
            float4 c0 = *reinterpret_cast<const float4*>(crow + 16);
            bf_[0]=c0.x; bf_[1]=c0.y;
        }
#pragma unroll
        for (int j = 0; j < 8; ++j) {
            float hf;
            bhi[mt][j] = bfhi(bf_[j], hf);
            blo[mt][j] = bflo(bf_[j], hf);
        }
        cn2m[mt] = crow[18];
    }

    // phase-2 accumulators: accA = d 0..15, accB = d 16..19 (19 = den)
    f32x4v accA[4], accB[4];
#pragma unroll
    for (int mt = 0; mt < 4; ++mt) {
        accA[mt] = (f32x4v){0.f,0.f,0.f,0.f};
        accB[mt] = (f32x4v){0.f,0.f,0.f,0.f};
    }

    __syncthreads();   // pls ready

#pragma unroll
    for (int pair = 0; pair < 4; ++pair) {
        const int pxt = pair*32;
        float e[2][4][4];
        float part[2][4];

        // ---- phase 1: two 16-px tiles ----
#pragma unroll
        for (int h = 0; h < 2; ++h) {
            const int pxb = pxt + h*16;
            float af[8];
#pragma unroll
            for (int j = 0; j < 8; ++j) af[j] = 0.f;
            const int abase = (pxb + al)*PROW;
            if (g < 2) {
                float4 x0 = *reinterpret_cast<const float4*>(&pls[abase + 8*g]);
                float4 x1 = *reinterpret_cast<const float4*>(&pls[abase + 8*g + 4]);
                af[0]=x0.x; af[1]=x0.y; af[2]=x0.z; af[3]=x0.w;
                af[4]=x1.x; af[5]=x1.y; af[6]=x1.z; af[7]=x1.w;
            } else if (g == 2) {
                float4 x0 = *reinterpret_cast<const float4*>(&pls[abase + 16]);
                af[0]=x0.x; af[1]=x0.y;
            }
            bf16x8 ahi, alo;
#pragma unroll
            for (int j = 0; j < 8; ++j) {
                float hf;
                ahi[j] = bfhi(af[j], hf);
                alo[j] = bflo(af[j], hf);
            }

            float pn2v[4];
#pragma unroll
            for (int r = 0; r < 4; ++r)
                pn2v[r] = pls[(pxb + 4*g + r)*PROW + 18];

#pragma unroll
            for (int mt = 0; mt < 4; ++mt) {
                f32x4v dt = {0.f, 0.f, 0.f, 0.f};
                dt = __builtin_amdgcn_mfma_f32_16x16x32_bf16(ahi, bhi[mt], dt, 0, 0, 0);
                dt = __builtin_amdgcn_mfma_f32_16x16x32_bf16(ahi, blo[mt], dt, 0, 0, 0);
                dt = __builtin_amdgcn_mfma_f32_16x16x32_bf16(alo, bhi[mt], dt, 0, 0, 0);
#pragma unroll
                for (int r = 0; r < 4; ++r) {
                    float d2 = fmaf(-2.f, dt[r], pn2v[r] + cn2m[mt]);
                    e[h][mt][r] = __expf(-__builtin_amdgcn_sqrtf(fmaxf(d2, 1e-12f)));
                }
            }
#pragma unroll
            for (int r = 0; r < 4; ++r)
                part[h][r] = (e[h][0][r] + e[h][1][r]) + (e[h][2][r] + e[h][3][r]);
        }

        // ---- softmax denominator: butterfly over al + cross-wave combine ----
#pragma unroll
        for (int mask = 1; mask <= 8; mask <<= 1) {
#pragma unroll
            for (int h = 0; h < 2; ++h)
#pragma unroll
                for (int r = 0; r < 4; ++r)
                    part[h][r] += __shfl_xor(part[h][r], mask);
        }
        if (al == 0) {
#pragma unroll
            for (int h = 0; h < 2; ++h)
#pragma unroll
                for (int r = 0; r < 4; ++r)
                    ssum_s[wv][h*16 + 4*g + r] = part[h][r];
        }
        __syncthreads();
        if (tid < 32)
            w_s[tid] = 1.0f / (ssum_s[0][tid] + ssum_s[1][tid]
                             + ssum_s[2][tid] + ssum_s[3][tid]);
        __syncthreads();

        // ---- phase 2: pp += ew · p  (one K=32 MFMA step over this pair) ----
        float w0[4], w1[4];
#pragma unroll
        for (int r = 0; r < 4; ++r) {
            w0[r] = w_s[4*g + r];
            w1[r] = w_s[16 + 4*g + r];
        }

        // B fragments: p columns at px = pxt + k, k-map k=4g+j / 16+4g+(j-4)
        bf16x8 p0h, p0l, p1h, p1l;
#pragma unroll
        for (int j = 0; j < 8; ++j) {
            const int px = pxt + ((j < 4) ? (4*g + j) : (16 + 4*g + (j-4)));
            float f0 = pls[px*PROW + al];
            float h0f;
            p0h[j] = bfhi(f0, h0f);
            p0l[j] = bflo(f0, h0f);
            float f1 = (al < 4) ? pls[px*PROW + 16 + al] : 0.f;
            float h1f;
            p1h[j] = bfhi(f1, h1f);
            p1l[j] = bflo(f1, h1f);
        }

#pragma unroll
        for (int mt = 0; mt < 4; ++mt) {
            // A fragment: ew for k-map px slots — phase-1 D rows align exactly
            bf16x8 awh, awl;
#pragma unroll
            for (int j = 0; j < 8; ++j) {
                float ev = (j < 4) ? e[0][mt][j] * w0[j]
                                   : e[1][mt][j-4] * w1[j-4];
                float hf;
                awh[j] = bfhi(ev, hf);
                awl[j] = bflo(ev, hf);
            }
            accA[mt] = __builtin_amdgcn_mfma_f32_16x16x32_bf16(awh, p0h, accA[mt], 0, 0, 0);
            accA[mt] = __builtin_amdgcn_mfma_f32_16x16x32_bf16(awh, p0l, accA[mt], 0, 0, 0);
            accA[mt] = __builtin_amdgcn_mfma_f32_16x16x32_bf16(awl, p0h, accA[mt], 0, 0, 0);
            accB[mt] = __builtin_amdgcn_mfma_f32_16x16x32_bf16(awh, p1h, accB[mt], 0, 0, 0);
            accB[mt] = __builtin_amdgcn_mfma_f32_16x16x32_bf16(awh, p1l, accB[mt], 0, 0, 0);
            accB[mt] = __builtin_amdgcn_mfma_f32_16x16x32_bf16(awl, p1h, accB[mt], 0, 0, 0);
        }
    }

    // ---- store pp: D layout row = 4g+reg (m within tile), col = al (d) ----
#pragma unroll
    for (int mt = 0; mt < 4; ++mt) {
#pragma unroll
        for (int r = 0; r < 4; ++r) {
            const int m = wv*64 + mt*16 + 4*g + r;
            float* dst = pp + ((size_t)(b*CHUNKS + chunk)*MM + m)*PROW;
            dst[al] = accA[mt][r];                 // d = 0..15
            if (al < 4) dst[16 + al] = accB[mt][r]; // d = 16..19 (19 = den)
        }
    }
}

// ---------------------------------------------------------------------------
// Final iteration kernel — barrier-free KM=4 VALU (best-measured, r14).
// ---------------------------------------------------------------------------
__device__ __forceinline__ void rowdot4(const float* __restrict__ prow,
                                        const f32x2 (&cp)[4][9], const float (&cn2)[4],
                                        float (&e)[4])
{
    const float4* pv = reinterpret_cast<const float4*>(prow);
    float4 q0 = pv[0], q1 = pv[1], q2 = pv[2], q3 = pv[3], q4 = pv[4];
    f32x2 u[9];
    u[0]=mk2(q0.x,q0.y); u[1]=mk2(q0.z,q0.w); u[2]=mk2(q1.x,q1.y);
    u[3]=mk2(q1.z,q1.w); u[4]=mk2(q2.x,q2.y); u[5]=mk2(q2.z,q2.w);
    u[6]=mk2(q3.x,q3.y); u[7]=mk2(q3.z,q3.w); u[8]=mk2(q4.x,q4.y);
    f32x2 d0=mk2(0.f,0.f), d1=mk2(0.f,0.f), d2=mk2(0.f,0.f), d3=mk2(0.f,0.f);
#pragma unroll
    for (int i = 0; i < 9; ++i) {
        d0 = pk_fma(u[i], cp[0][i], d0);
        d1 = pk_fma(u[i], cp[1][i], d1);
        d2 = pk_fma(u[i], cp[2][i], d2);
        d3 = pk_fma(u[i], cp[3][i], d3);
    }
    float s0 = fmaf(-2.f, d0.x + d0.y, q4.z + cn2[0]);
    float s1 = fmaf(-2.f, d1.x + d1.y, q4.z + cn2[1]);
    float s2 = fmaf(-2.f, d2.x + d2.y, q4.z + cn2[2]);
    float s3 = fmaf(-2.f, d3.x + d3.y, q4.z + cn2[3]);
    e[0] = __expf(-__builtin_amdgcn_sqrtf(fmaxf(s0, 1e-12f)));
    e[1] = __expf(-__builtin_amdgcn_sqrtf(fmaxf(s1, 1e-12f)));
    e[2] = __expf(-__builtin_amdgcn_sqrtf(fmaxf(s2, 1e-12f)));
    e[3] = __expf(-__builtin_amdgcn_sqrtf(fmaxf(s3, 1e-12f)));
}

#define RS8(L, s) \
    { const bool hi = ((L) & 1); \
      _Pragma("unroll") for (int k = 0; k < 4; ++k) { \
        float a = s[k], bq = s[k+4]; \
        float recv = __shfl_xor(hi ? a : bq, 1); \
        s[k] = (hi ? bq : a) + recv; } } \
    { const bool hi = ((L) & 2); \
      _Pragma("unroll") for (int k = 0; k < 2; ++k) { \
        float a = s[k], bq = s[k+2]; \
        float recv = __shfl_xor(hi ? a : bq, 2); \
        s[k] = (hi ? bq : a) + recv; } } \
    { const bool hi = ((L) & 4); \
      { float a = s[0], bq = s[1]; \
        float recv = __shfl_xor(hi ? a : bq, 4); \
        s[0] = (hi ? bq : a) + recv; } } \
    s[0] += __shfl_xor(s[0], 8); \
    s[0] += __shfl_xor(s[0], 16); \
    s[0] += __shfl_xor(s[0], 32);

__global__ __launch_bounds__(256, 3)
void ssn_fin(const float* __restrict__ ptbuf, const float* __restrict__ cbuf,
             float* __restrict__ qout)
{
    __shared__ __align__(16) float pls[PIXPERBLK*PROW];   // 10240 B

    const int tid    = threadIdx.x;
    const int b      = blockIdx.x >> 9;
    const int chunk  = blockIdx.x & (CHUNKS-1);
    const int n_base = chunk * PIXPERBLK;
    const int L      = tid & 63;
    const int wv     = tid >> 6;

    {
        const float4* src = reinterpret_cast<const float4*>(
            ptbuf + (size_t)(b*NN + n_base)*PROW);
#pragma unroll
        for (int k = 0; k < 3; ++k) {
            int f = tid + (k << 8);
            if (f < PIXPERBLK*PROW/4)
                reinterpret_cast<float4*>(pls)[f] = src[f];
        }
    }

    // centers m = 4L + j  (lane-contiguous -> float4 Q store)
    f32x2 cp[4][9]; float cn2[4];
#pragma unroll
    for (int j = 0; j < 4; ++j) {
        const float4* cv = reinterpret_cast<const float4*>(
            cbuf + (b*MM + 4*L + j)*CROW);
        float4 a0 = cv[0], a1 = cv[1], a2 = cv[2], a3 = cv[3], a4 = cv[4];
        cp[j][0]=mk2(a0.x,a0.y); cp[j][1]=mk2(a0.z,a0.w);
        cp[j][2]=mk2(a1.x,a1.y); cp[j][3]=mk2(a1.z,a1.w);
        cp[j][4]=mk2(a2.x,a2.y); cp[j][5]=mk2(a2.z,a2.w);
        cp[j][6]=mk2(a3.x,a3.y); cp[j][7]=mk2(a3.z,a3.w);
        cp[j][8]=mk2(a4.x,a4.y); cn2[j]=a4.z;
    }

    __syncthreads();   // pls ready

    for (int t = 0; t < TSUB; ++t) {
        const int pxb = t*PIX + wv*8;

        float e[4][8];
        float s[8];
#pragma unroll
        for (int k = 0; k < 8; ++k) {
            float ek[4];
            rowdot4(&pls[(pxb + k)*PROW], cp, cn2, ek);
            e[0][k] = ek[0]; e[1][k] = ek[1]; e[2][k] = ek[2]; e[3][k] = ek[3];
            s[k] = (ek[0] + ek[1]) + (ek[2] + ek[3]);
        }

        RS8(L, s)
        float wr = 1.0f / s[0];
        float w[8];
#pragma unroll
        for (int k = 0; k < 8; ++k)
            w[k] = __shfl(wr, ((k&1)<<2) | (k&2) | ((k>>2)&1));

#pragma unroll
        for (int k = 0; k < 8; ++k) {
            size_t rowoff = ((size_t)(b*NN + n_base + pxb + k)) << 8;
            float4 qv = make_float4(e[0][k]*w[k], e[1][k]*w[k],
                                    e[2][k]*w[k], e[3][k]*w[k]);
            *reinterpret_cast<float4*>(qout + rowoff + 4*L) = qv;
        }
    }
}

// ---------------------------------------------------------------------------
// Sum the 512 per-chunk partials for each (b,m); produce new centers row.
// pp layout: slots 0..17 = num, 18 = junk (Sum ew*pn2), 19 = den.
// ---------------------------------------------------------------------------
__global__ __launch_bounds__(256)
void reduce_finalize(const float* __restrict__ pp, float* __restrict__ cbuf,
                     float* __restrict__ cfout, int write_cf)
{
    const int b   = blockIdx.x >> 8;
    const int m   = blockIdx.x & 255;
    const int tid = threadIdx.x;
    const int lane = tid & 63, wv = tid >> 6;

    const float4* r0 = reinterpret_cast<const float4*>(
        pp + ((size_t)(b*CHUNKS + tid)*MM + m)*PROW);
    const float4* r1 = reinterpret_cast<const float4*>(
        pp + ((size_t)(b*CHUNKS + tid + 256)*MM + m)*PROW);
    float a[20];
    {
        float4 u0=r0[0], u1=r0[1], u2=r0[2], u3=r0[3], u4=r0[4];
        float4 w0=r1[0], w1=r1[1], w2=r1[2], w3=r1[3], w4=r1[4];
        a[0]=u0.x+w0.x;  a[1]=u0.y+w0.y;  a[2]=u0.z+w0.z;  a[3]=u0.w+w0.w;
        a[4]=u1.x+w1.x;  a[5]=u1.y+w1.y;  a[6]=u1.z+w1.z;  a[7]=u1.w+w1.w;
        a[8]=u2.x+w2.x;  a[9]=u2.y+w2.y;  a[10]=u2.z+w2.z; a[11]=u2.w+w2.w;
        a[12]=u3.x+w3.x; a[13]=u3.y+w3.y; a[14]=u3.z+w3.z; a[15]=u3.w+w3.w;
        a[16]=u4.x+w4.x; a[17]=u4.y+w4.y; a[18]=u4.z+w4.z; a[19]=u4.w+w4.w;
    }
#pragma unroll
    for (int off = 32; off; off >>= 1) {
#pragma unroll
        for (int d = 0; d < 20; ++d) a[d] += __shfl_down(a[d], off);
    }

    __shared__ float red[4][20];
    if (lane == 0) {
#pragma unroll
        for (int d = 0; d < 20; ++d) red[wv][d] = a[d];
    }
    __syncthreads();
    if (tid == 0) {
        float s[20];
#pragma unroll
        for (int d = 0; d < 20; ++d)
            s[d] = red[0][d] + red[1][d] + red[2][d] + red[3][d];
        float den = s[19] + 1e-6f;
        float* row = cbuf + (b*MM + m)*CROW;
        float cn2 = 0.f;
#pragma unroll
        for (int d = 0; d < 18; ++d) {
            float cv = s[d] / den;
            row[d] = cv;
            cn2 = fmaf(cv, cv, cn2);
            if (write_cf && d < 16) cfout[((b*CC + d) << 8) + m] = cv;
        }
        row[18] = cn2;
        row[19] = 0.f;
    }
}

// ---------------------------------------------------------------------------
extern "C" void kernel_launch(void* const* d_in, const int* in_sizes, int n_in,
                              void* d_out, int out_size, void* d_ws, size_t ws_size,
                              hipStream_t stream)
{
    const float* feat = (const float*)d_in[0];
    float* dout = (float*)d_out;

    // d_ws layout: cbuf (128 KB) | ptbuf 21 MB | pp 42 MB
    float* cbuf  = (float*)d_ws;
    float* ptbuf = cbuf + 32768;
    float* pp    = ptbuf + (size_t)BB*NN*PROW;

    float* qout  = dout;                                // [B, N, M]
    float* cfout = dout + (size_t)BB*NN*MM;             // [B, C, M]

    build_pt<<<dim3(BB*256), dim3(256), 0, stream>>>(feat, ptbuf);
    init_centers<<<dim3(BB*MM), dim3(64), 0, stream>>>(feat, cbuf);

    for (int it = 0; it < 2; ++it) {
        ssn_nf<<<dim3(BB*CHUNKS), dim3(256), 0, stream>>>(ptbuf, cbuf, pp);
        reduce_finalize<<<dim3(BB*MM), dim3(256), 0, stream>>>(pp, cbuf, cfout, it == 1);
    }
    ssn_fin<<<dim3(BB*CHUNKS), dim3(256), 0, stream>>>(ptbuf, cbuf, qout);
}